// Round 7
// baseline (2489.695 us; speedup 1.0000x reference)
//
#include <hip/hip_runtime.h>

// Shapes: BS=256, C=256, H=W=16, HW=256, conv1: 1024->1024 3x3, conv2: 1024->512 3x3,
// cls: 512->512 1x1 (only diagonal of PSROI needed -> 2 dots/pixel).
//
// Workspace layout (bytes):
//   featT  @ 0          : bf16 [256 b][256 p][1024 ch]  = 134217728   (ch: r1|corr1|r2|corr2)
//   out1T  @ 134217728  : bf16 [256 b][256 p][1024 o]   = 134217728
//   W1b    @ 268435456  : bf16 [9][1024][1024]          = 18874368
//   W2b    @ 287309824  : bf16 [9][512][1024]           = 9437184
//   s1     @ 296747008  : f32  [256*256]                = 262144
//   s2     @ 297009152  : f32  [256*256]                = 262144
//   out2T  @ 0 (overlays featT, dead after conv1): bf16 [256][256][512] = 67108864
//
// SWIZZLED STORAGE FORMAT: every bf16 row-major tensor stores each 64B slice
// (4 x 16B chunks) with chunk index XORed by ((row>>1)&3), row = pixel p or
// out-channel o. Conflict-light LDS b128 reads with monotonic gl2lds staging;
// conv epilogue emits merged uint4 stores (full-line write combine).
//
// r7 conv: r4 geometry (512 thr, 8 waves of 64x64, 16x16x32, read+MFMA in the
// same step) but TWO TAPS PER BARRIER STEP. r4 PMC: MFMA 62% / LDS 54% of the
// per-step window -> ~38% dead time from the per-tap barrier cadence (288
// shallow steps). Now 9 steps per 2-kc superstep (16 reads + 32 MFMA deep),
// half the barriers. LDS trimmed to exactly 64KB (2 blocks/CU preserved --
// r6 showed 1 block/CU costs ~25%): X 2x256 rows (border masking moved to
// branchless VALU msk instead of a zero row) + W 2 bufsets x 2 tap slots.
// W prefetch depth-1 intra-step (issue at step top, drain at step end; L2-hit
// latency ~350cy << step ~1-2kcy). X staged at s=0 (kc+1) / s=5 (kc+2), 4
// steps of slack. vmcnt(2) at s in {0,5}, else vmcnt(0) (drains only loads
// issued this step). All WAR windows barrier-separated (audited).

typedef __attribute__((ext_vector_type(8))) __bf16 bf16x8;
typedef __attribute__((ext_vector_type(4))) float f32x4;
typedef unsigned short u16;

template <bool B> struct BC { static constexpr bool value = B; };

__device__ __forceinline__ u16 f2bf(float f) {
  union { float f; unsigned u; } v; v.f = f;
  unsigned u = v.u;
  u += 0x7fffu + ((u >> 16) & 1u);   // RNE
  return (u16)(u >> 16);
}
__device__ __forceinline__ float bf2f(u16 h) {
  union { unsigned u; float f; } v; v.u = ((unsigned)h) << 16;
  return v.f;
}
__device__ __forceinline__ void gl2lds16(const void* g, void* l) {
  __builtin_amdgcn_global_load_lds(
      (__attribute__((address_space(1))) void*)(void*)g,
      (__attribute__((address_space(3))) void*)l, 16, 0, 0);
}

// ---------------------------------------------------------------------------
// Kernel 1: relu + channel-L2-norm scales + bf16 transpose to featT[b][p][ch].
// Stores in swizzled format: ch' = ch ^ (((p>>1)&3)<<3).
__global__ __launch_bounds__(256) void k_norm(const float* __restrict__ f1,
                                              const float* __restrict__ f2,
                                              u16* __restrict__ featT,
                                              float* __restrict__ s1,
                                              float* __restrict__ s2) {
  int bx = blockIdx.x;
  int b = bx >> 2;
  int p0 = (bx & 3) << 6;
  int t = threadIdx.x;
  int p = p0 + (t & 63);
  int cg = t >> 6;
  int sp3 = ((p >> 1) & 3) << 3;
  const float* F1 = f1 + ((size_t)b << 16);
  const float* F2 = f2 + ((size_t)b << 16);
  u16* FT = featT + (((size_t)(b << 8) + p) << 10);
  float ss1 = 0.f, ss2 = 0.f;
  for (int i = 0; i < 64; ++i) {
    int c = (cg << 6) + i;
    float v1 = F1[(c << 8) + p]; v1 = v1 > 0.f ? v1 : 0.f;
    float v2 = F2[(c << 8) + p]; v2 = v2 > 0.f ? v2 : 0.f;
    ss1 += v1 * v1; ss2 += v2 * v2;
    FT[c ^ sp3] = f2bf(v1);
    FT[512 + (c ^ sp3)] = f2bf(v2);
  }
  __shared__ float l1[256], l2[256];
  l1[t] = ss1; l2[t] = ss2;
  __syncthreads();
  if (t < 64) {
    float a = l1[t] + l1[t + 64] + l1[t + 128] + l1[t + 192];
    float c2 = l2[t] + l2[t + 64] + l2[t + 128] + l2[t + 192];
    int pp = (b << 8) + p0 + t;
    s1[pp] = 1.f / fmaxf(sqrtf(a), 1e-12f);
    s2[pp] = 1.f / fmaxf(sqrtf(c2), 1e-12f);
  }
}

// ---------------------------------------------------------------------------
// Kernel 2: weight repack fp32 [O][C][3][3] -> bf16 [tap][O][C], swizzled:
// c' = c ^ (((o>>1)&3)<<3).
__global__ __launch_bounds__(256) void k_wconv(const float* __restrict__ w,
                                               u16* __restrict__ wb, int O, int C) {
  int o = blockIdx.x;
  int t = threadIdx.x;
  int sp3 = ((o >> 1) & 3) << 3;
  const float* src = w + (size_t)o * C * 9;
  for (int c = t; c < C; c += 256) {
    const float* s = src + c * 9;
    float v[9];
#pragma unroll
    for (int i = 0; i < 9; ++i) v[i] = s[i];
#pragma unroll
    for (int tap = 0; tap < 9; ++tap)
      wb[(size_t)tap * O * C + (size_t)o * C + (c ^ sp3)] = f2bf(v[tap]);
  }
}

// ---------------------------------------------------------------------------
// Kernel 3: Gram GEMM G[p1][p2] = sum_c r1[p1][c]*r2[p2][c], scaled epilogue.
// (unchanged r4: 16x16x32 MFMA, monotonic staging, swizzled read chunk)
__global__ __launch_bounds__(256) void k_corr(u16* featT,
                                              const float* __restrict__ s1,
                                              const float* __restrict__ s2,
                                              float* __restrict__ out) {
  __shared__ alignas(16) u16 Alds[128 * 32];
  __shared__ alignas(16) u16 Blds[128 * 32];
  __shared__ float tb[4][16][66];
  int bx = blockIdx.x;
  int b = bx >> 2;
  int p1b = ((bx >> 1) & 1) << 7;
  int p2b = (bx & 1) << 7;
  int t = threadIdx.x, l = t & 63, w = t >> 6;
  int wm = w >> 1, wn = w & 1, lr = l & 15, lq = l >> 4;
  int srow = (w << 4) + (l >> 2);
  int sq = (l & 3) << 3;                       // monotonic source chunk
  int rsz = ((lq ^ ((lr >> 1) & 3)) << 3);     // swizzled read chunk
  const size_t bbase = (size_t)b << 18;

  f32x4 acc[4][4];
#pragma unroll
  for (int i = 0; i < 4; ++i)
#pragma unroll
    for (int j = 0; j < 4; ++j) acc[i][j] = (f32x4){0.f, 0.f, 0.f, 0.f};

#pragma unroll 1
  for (int kc = 0; kc < 8; ++kc) {
    int c0 = kc << 5;
    const u16* sA = featT + bbase + ((size_t)(p1b + srow) << 10) + (c0 + sq);
    gl2lds16(sA, Alds + ((w << 4) << 5));
    gl2lds16(sA + (64 << 10), Alds + ((64 + (w << 4)) << 5));
    const u16* sB = featT + bbase + ((size_t)(p2b + srow) << 10) + (512 + c0 + sq);
    gl2lds16(sB, Blds + ((w << 4) << 5));
    gl2lds16(sB + (64 << 10), Blds + ((64 + (w << 4)) << 5));
    __syncthreads();
    bf16x8 af[4], bfr[4];
#pragma unroll
    for (int mf = 0; mf < 4; ++mf)
      af[mf] = *(const bf16x8*)(Alds + (((wm << 6) + (mf << 4) + lr) << 5) + rsz);
#pragma unroll
    for (int nf = 0; nf < 4; ++nf)
      bfr[nf] = *(const bf16x8*)(Blds + (((wn << 6) + (nf << 4) + lr) << 5) + rsz);
#pragma unroll
    for (int mf = 0; mf < 4; ++mf)
#pragma unroll
      for (int nf = 0; nf < 4; ++nf)
        acc[mf][nf] = __builtin_amdgcn_mfma_f32_16x16x32_bf16(af[mf], bfr[nf], acc[mf][nf], 0, 0, 0);
    __syncthreads();
  }

  float sc2[4]; int p2g[4];
#pragma unroll
  for (int nf = 0; nf < 4; ++nf) {
    int p2 = p2b + (wn << 6) + (nf << 4) + lr;
    p2g[nf] = p2;
    sc2[nf] = s2[(b << 8) + p2];
  }
  float* corr1 = out + 512;
  float* corr2 = out + 512 + 16777216;
#pragma unroll
  for (int mf = 0; mf < 4; ++mf) {
    float gv[4][4];
#pragma unroll
    for (int r = 0; r < 4; ++r) {
      int p1 = p1b + (wm << 6) + (mf << 4) + (lq << 2) + r;
      float s1v = s1[(b << 8) + p1];
#pragma unroll
      for (int nf = 0; nf < 4; ++nf) gv[nf][r] = acc[mf][nf][r] * s1v * sc2[nf];
    }
#pragma unroll
    for (int r = 0; r < 4; ++r) {
      int p1 = p1b + (wm << 6) + (mf << 4) + (lq << 2) + r;
      int s1p3 = ((p1 >> 1) & 3) << 3;
#pragma unroll
      for (int nf = 0; nf < 4; ++nf) {
        corr2[((size_t)b << 16) + ((size_t)p1 << 8) + p2g[nf]] = gv[nf][r];
        featT[bbase + ((size_t)p1 << 10) + 256 + (p2g[nf] ^ s1p3)] = f2bf(gv[nf][r]);
      }
    }
#pragma unroll
    for (int r = 0; r < 4; ++r)
#pragma unroll
      for (int nf = 0; nf < 4; ++nf)
        tb[w][(lq << 2) + r][(nf << 4) + lr] = gv[nf][r];
#pragma unroll
    for (int j = 0; j < 16; ++j) {
      float v = tb[w][lr][(j << 2) + lq];
      int p2 = p2b + (wn << 6) + (j << 2) + lq;
      int s2p3 = ((p2 >> 1) & 3) << 3;
      int p1 = p1b + (wm << 6) + (mf << 4) + lr;
      corr1[((size_t)b << 16) + ((size_t)p2 << 8) + p1] = v;
      featT[bbase + ((size_t)p2 << 10) + 768 + (p1 ^ s2p3)] = f2bf(v);
    }
  }
}

// ---------------------------------------------------------------------------
// Kernel 4/5: implicit-GEMM 3x3 conv, 2 taps per barrier step (see header).
// Block = whole image M=256 x N=128 o, 512 threads = 8 waves (4M x 2N) 64x64.
// Superstep = 2 kc (18 taps) = 9 steps. Step s computes taps g=2s,2s+1
// (tap = g%9, X parity = (g/9)&1), stages W(step s+1) into bufset
// (PAR+s+1)&1 (PAR = superstep parity), stages X(kc+1) at s=0 / X(kc+2) at
// s=5. Border masking: branchless msk on LDS address + data (no zero row).
// Epilogue: per-wave LDS transpose -> merged uint4 stores in swizzled format.
template <int O, int OTB>
__global__ __launch_bounds__(512, 4) void k_conv(const u16* __restrict__ X,
                                                 const u16* __restrict__ Wb,
                                                 const float* __restrict__ bias,
                                                 u16* __restrict__ Out) {
  __shared__ alignas(16) u16 Xlds[2][256 * 32];      // 32 KB (no zero row)
  __shared__ alignas(16) u16 Wlds[2][2][128 * 32];   // 32 KB: [bufset][tap slot]
  int bx = blockIdx.x;
  int otile = bx & ((1 << OTB) - 1);   // low bits -> XCD affinity for the W slice
  int b = bx >> OTB;
  int t = threadIdx.x, l = t & 63, w = t >> 6;
  int wm = w & 3, wn = w >> 2;
  int lr = l & 15, lq = l >> 4;
  int o0 = otile << 7;
  int srl = l >> 2;
  int sq = (l & 3) << 3;               // monotonic source chunk
  const size_t xbase = (size_t)b << 18;

  const u16* wsrc = Wb + (((size_t)(o0 + (w << 4) + srl)) << 10) + sq;
  const u16* xsrc0 = X + xbase + (((size_t)((w << 4) + srl)) << 10) + sq;
  const u16* xsrc1 = xsrc0 + ((size_t)128 << 10);

  u16* xdb = &Xlds[0][0];
  u16* wdb = &Wlds[0][0][0];
  const int wdo = (w << 4) << 5;            // staging dest offset within a slot
  const int xdo0 = (w << 4) << 5;
  const int xdo1 = (128 + (w << 4)) << 5;

  // W read base: row = (wn<<6)+(nf<<4)+lr -> stored swizzle term ((lr>>1)&3).
  int rszw = ((lq ^ ((lr >> 1) & 3)) << 3);
  const int wro = (((wn << 6) + lr) << 5) + rszw;

  int pb[4];
#pragma unroll
  for (int mf = 0; mf < 4; ++mf)
    pb[mf] = (((wm << 6) + (mf << 4) + lr) << 5);
  int xsz[3];
#pragma unroll
  for (int d = 0; d < 3; ++d)
    xsz[d] = ((lq ^ (((lr + d - 1) >> 1) & 3)) << 3);

  f32x4 acc[4][4];
#pragma unroll
  for (int i = 0; i < 4; ++i)
#pragma unroll
    for (int j = 0; j < 4; ++j) acc[i][j] = (f32x4){0.f, 0.f, 0.f, 0.f};

  // prologue: X(0) -> par0; W taps 0,1 -> bufset0 slots 0,1
  gl2lds16(xsrc0, xdb + xdo0);
  gl2lds16(xsrc1, xdb + xdo1);
  gl2lds16(wsrc, wdb + wdo);
  gl2lds16(wsrc + ((size_t)O << 10), wdb + 4096 + wdo);
  asm volatile("s_waitcnt vmcnt(0)" ::: "memory");
  __builtin_amdgcn_s_barrier();

  auto sstep = [&](auto parc, int kc) {   // one superstep: kc, kc+1 (kc even)
    constexpr int PAR = decltype(parc)::value ? 1 : 0;
#pragma unroll
    for (int s = 0; s < 9; ++s) {
      __builtin_amdgcn_sched_barrier(0);
      const int wbs_rd = (PAR + s) & 1;
      const int wbs_wr = wbs_rd ^ 1;
      // --- stage W for step s+1 (two taps; wraps into next kc / superstep) ---
#pragma unroll
      for (int i = 0; i < 2; ++i) {
        const int gg = 2 * s + 2 + i;
        const int ntap = gg % 9;
        const int dk = gg / 9;          // tail reads in-ws garbage (dead)
        gl2lds16(wsrc + (size_t)ntap * ((size_t)O << 10) + ((kc + dk) << 5),
                 wdb + wbs_wr * 8192 + i * 4096 + wdo);
      }
      if (s == 0) {   // X(kc+1) -> par1 (read from s=4; WAR: par1 last read prev s=8)
        gl2lds16(xsrc0 + ((kc + 1) << 5), xdb + 8192 + xdo0);
        gl2lds16(xsrc1 + ((kc + 1) << 5), xdb + 8192 + xdo1);
      }
      if (s == 5) {   // X(kc+2) -> par0 (read next superstep s=0; WAR: last read s=4)
        gl2lds16(xsrc0 + ((kc + 2) << 5), xdb + xdo0);
        gl2lds16(xsrc1 + ((kc + 2) << 5), xdb + xdo1);
      }
      // --- two taps of compute (compiler interleaves reads/MFMAs freely) ---
#pragma unroll
      for (int i = 0; i < 2; ++i) {
        const int g = 2 * s + i;
        const int tap = g % 9;
        const int xpar = (g / 9) & 1;
        const int dr = tap / 3 - 1, dc = tap % 3 - 1;
        const u16* wr = wdb + wbs_rd * 8192 + i * 4096 + wro;
        bf16x8 bw[4];
#pragma unroll
        for (int nf = 0; nf < 4; ++nf) bw[nf] = *(const bf16x8*)(wr + (nf << 9));
        const u16* xr = xdb + xpar * 8192;
        const int dpo = ((dr << 4) + dc) << 5;
        bf16x8 a[4];
#pragma unroll
        for (int mf = 0; mf < 4; ++mf) {
          bool ok = (((unsigned)((wm << 2) + mf + dr) < 16u) &
                     ((unsigned)(lr + dc) < 16u));
          int msk = ok ? -1 : 0;
          uint4 u = *(const uint4*)(xr + ((pb[mf] + dpo + xsz[dc + 1]) & msk));
          u.x &= msk; u.y &= msk; u.z &= msk; u.w &= msk;
          a[mf] = *(const bf16x8*)&u;
        }
#pragma unroll
        for (int mf = 0; mf < 4; ++mf)
#pragma unroll
          for (int nf = 0; nf < 4; ++nf)
            acc[mf][nf] = __builtin_amdgcn_mfma_f32_16x16x32_bf16(a[mf], bw[nf], acc[mf][nf], 0, 0, 0);
      }
      // --- waits: drain this step's W stage (+X stays in flight at s=0,5);
      // lgkmcnt(0) = all frag reads retired (WAR vs next step's gl2lds).
      if (s == 0 || s == 5) asm volatile("s_waitcnt vmcnt(2) lgkmcnt(0)" ::: "memory");
      else                  asm volatile("s_waitcnt vmcnt(0) lgkmcnt(0)" ::: "memory");
      __builtin_amdgcn_s_barrier();
    }
  };

#pragma unroll 1
  for (int S2 = 0; S2 < 8; ++S2) {
    sstep(BC<false>{}, 4 * S2);
    sstep(BC<true>{}, 4 * S2 + 2);
  }

  // ---- epilogue: per-wave LDS transpose -> vectorized swizzled stores ----
  __syncthreads();   // drains dangling prefetch; LDS reusable as scratch
  float bv[4];
#pragma unroll
  for (int nf = 0; nf < 4; ++nf) bv[nf] = bias[o0 + (wn << 6) + (nf << 4) + lr];
  u16* scr = ((u16*)Xlds) + w * 1152;   // per-wave 16 rows x 72 u16
  int rr2 = l >> 2;                     // 4 lanes per row
  int kq = l & 3;
#pragma unroll
  for (int mf = 0; mf < 4; ++mf) {
#pragma unroll
    for (int r = 0; r < 4; ++r) {
      int rr = (lq << 2) + r;
#pragma unroll
      for (int nf = 0; nf < 4; ++nf) {
        float vv = acc[mf][nf][r] + bv[nf];
        scr[rr * 72 + (nf << 4) + lr] = f2bf(vv > 0.f ? vv : 0.f);
      }
    }
    asm volatile("s_waitcnt lgkmcnt(0)" ::: "memory");
    __builtin_amdgcn_sched_barrier(0);
    int p = (wm << 6) + (mf << 4) + rr2;
    int sp = (p >> 1) & 3;
    size_t rbase = (size_t)((b << 8) + p) * O + (size_t)(o0 + (wn << 6));
#pragma unroll
    for (int j = 0; j < 2; ++j) {
      int k = (j << 2) | kq;             // stored chunk (monotone per group)
      int kl = (j << 2) | (kq ^ sp);     // logical chunk held at stored slot k
      uint4 v = *(const uint4*)(scr + rr2 * 72 + (kl << 3));
      *(uint4*)(Out + rbase + (k << 3)) = v;
    }
    asm volatile("s_waitcnt lgkmcnt(0)" ::: "memory");
    __builtin_amdgcn_sched_barrier(0);
  }
}

// ---------------------------------------------------------------------------
// Kernel 6: cls head. score[b][c] = mean_p relu(dot(out2T[b][p], Wc[c*256+p])),
// softmax over c. X2 rows swizzled: read stored chunks MONOTONICALLY (coalesced)
// and permute the WEIGHT chunk index instead (w reads are per-lane scattered
// rows anyway, so the permutation is free).
__global__ __launch_bounds__(256) void k_cls(const u16* __restrict__ X2,
                                             const float* __restrict__ Wc,
                                             float* __restrict__ out) {
  int b = blockIdx.x, p = threadIdx.x;
  int s = (p >> 1) & 3;
  const uint4* xv = (const uint4*)(X2 + (((size_t)(b << 8) + p) << 9));
  const float4* w0 = (const float4*)(Wc + ((size_t)p << 9));
  const float4* w1 = (const float4*)(Wc + ((size_t)(256 + p) << 9));
  float a0 = 0.f, a1 = 0.f;
#pragma unroll 4
  for (int i = 0; i < 64; ++i) {
    uint4 u = xv[i];                      // monotonic stored chunk
    int il = (i & ~3) | ((i & 3) ^ s);    // logical chunk held at stored slot i
    float x0 = bf2f((u16)(u.x & 0xffffu)), x1 = bf2f((u16)(u.x >> 16));
    float x2 = bf2f((u16)(u.y & 0xffffu)), x3 = bf2f((u16)(u.y >> 16));
    float x4 = bf2f((u16)(u.z & 0xffffu)), x5 = bf2f((u16)(u.z >> 16));
    float x6 = bf2f((u16)(u.w & 0xffffu)), x7 = bf2f((u16)(u.w >> 16));
    float4 wa = w0[il * 2], wb = w0[il * 2 + 1];
    a0 += x0 * wa.x + x1 * wa.y + x2 * wa.z + x3 * wa.w +
          x4 * wb.x + x5 * wb.y + x6 * wb.z + x7 * wb.w;
    float4 wc4 = w1[il * 2], wd = w1[il * 2 + 1];
    a1 += x0 * wc4.x + x1 * wc4.y + x2 * wc4.z + x3 * wc4.w +
          x4 * wd.x + x5 * wd.y + x6 * wd.z + x7 * wd.w;
  }
  a0 = fmaxf(a0, 0.f);
  a1 = fmaxf(a1, 0.f);
  __shared__ float r0[256], r1[256];
  r0[p] = a0; r1[p] = a1;
  for (int sdx = 128; sdx > 0; sdx >>= 1) {
    __syncthreads();
    if (p < sdx) { r0[p] += r0[p + sdx]; r1[p] += r1[p + sdx]; }
  }
  __syncthreads();
  if (p == 0) {
    float s0 = r0[0] * (1.f / 256.f), s1v = r1[0] * (1.f / 256.f);
    float m = fmaxf(s0, s1v);
    float e0 = expf(s0 - m), e1 = expf(s1v - m);
    float inv = 1.f / (e0 + e1);
    out[(b << 1) + 0] = e0 * inv;
    out[(b << 1) + 1] = e1 * inv;
  }
}

// ---------------------------------------------------------------------------
extern "C" void kernel_launch(void* const* d_in, const int* in_sizes, int n_in,
                              void* d_out, int out_size, void* d_ws, size_t ws_size,
                              hipStream_t stream) {
  const float* f1 = (const float*)d_in[0];
  const float* f2 = (const float*)d_in[1];
  const float* w1 = (const float*)d_in[2];
  const float* b1 = (const float*)d_in[3];
  const float* w2 = (const float*)d_in[4];
  const float* b2 = (const float*)d_in[5];
  const float* wc = (const float*)d_in[6];
  float* out = (float*)d_out;
  char* ws = (char*)d_ws;

  u16* featT = (u16*)(ws + 0);
  u16* out1T = (u16*)(ws + 134217728);
  u16* W1b   = (u16*)(ws + 268435456);
  u16* W2b   = (u16*)(ws + 287309824);
  float* s1  = (float*)(ws + 296747008);
  float* s2  = (float*)(ws + 297009152);
  u16* out2T = (u16*)(ws + 0);  // overlays featT (dead after conv1)

  k_norm<<<1024, 256, 0, stream>>>(f1, f2, featT, s1, s2);
  k_wconv<<<1024, 256, 0, stream>>>(w1, W1b, 1024, 1024);
  k_wconv<<<512, 256, 0, stream>>>(w2, W2b, 512, 1024);
  k_corr<<<1024, 256, 0, stream>>>(featT, s1, s2, out);
  k_conv<1024, 3><<<2048, 512, 0, stream>>>(featT, W1b, b1, out1T);
  k_conv<512, 2><<<1024, 512, 0, stream>>>(out1T, W2b, b2, out2T);
  k_cls<<<256, 256, 0, stream>>>(out2T, wc, out);
}

// Round 8
// 2250.362 us; speedup vs baseline: 1.1064x; 1.1064x over previous
//
#include <hip/hip_runtime.h>

// Shapes: BS=256, C=256, H=W=16, HW=256, conv1: 1024->1024 3x3, conv2: 1024->512 3x3,
// cls: 512->512 1x1 (only diagonal of PSROI needed -> 2 dots/pixel).
//
// Workspace layout (bytes):
//   featT  @ 0          : bf16 [256 b][256 p][1024 ch]  = 134217728   (ch: r1|corr1|r2|corr2)
//   out1T  @ 134217728  : bf16 [256 b][256 p][1024 o]   = 134217728
//   W1b    @ 268435456  : bf16 [9][1024][1024]          = 18874368
//   W2b    @ 287309824  : bf16 [9][512][1024]           = 9437184
//   s1     @ 296747008  : f32  [256*256]                = 262144
//   s2     @ 297009152  : f32  [256*256]                = 262144
//   out2T  @ 0 (overlays featT, dead after conv1): bf16 [256][256][512] = 67108864
//
// SWIZZLED STORAGE FORMAT: every bf16 row-major tensor stores each 64B slice
// (4 x 16B chunks) with chunk index XORed by ((row>>1)&3), row = pixel p or
// out-channel o. Conflict-light LDS b128 reads with monotonic gl2lds staging;
// conv epilogue emits merged uint4 stores (full-line write combine).
//
// r8 conv = r4 (the best measured config: per-tap barrier, 512 thr / 8 waves of
// 64x64, 16x16x32 MFMA, counted vmcnt, 2 blocks/CU) + W prefetch depth 2 -> 3
// (4 bufs, buf = (kc+tap)&3, kc%4-templated body) + s_setprio(1) around MFMAs.
// r5 (1 blk/CU big tiles), r6 (reg pipeline), r7 (fat phases, depth-1 W) all
// regressed: cross-block overlap at 2 blocks/CU + deep W prefetch are the
// load-bearing features. Depth-3 gives W ~2400cy of landing slack (covers L3/
// HBM-miss), attacking the residual barrier-wait stall identified in r4 PMC.
// FIFO audit (per wave, 1 W load/step, X pair at tap0):
//   T0: queue W1,W2,+W3,X,X -> need W1 -> vmcnt(4)
//   T1: W2,W3,X,X,+W4      -> need W2 -> vmcnt(4)
//   T2: W3,X,X,W4,+W5      -> need W3 -> vmcnt(4)
//   T3: X,X,W4,W5,+W6      -> need W4 -> vmcnt(2) (drains X; X read 6 steps later)
//   T4-T8: vmcnt(2)

typedef __attribute__((ext_vector_type(8))) __bf16 bf16x8;
typedef __attribute__((ext_vector_type(4))) float f32x4;
typedef unsigned short u16;

template <int I> struct IC { static constexpr int value = I; };

__device__ __forceinline__ u16 f2bf(float f) {
  union { float f; unsigned u; } v; v.f = f;
  unsigned u = v.u;
  u += 0x7fffu + ((u >> 16) & 1u);   // RNE
  return (u16)(u >> 16);
}
__device__ __forceinline__ float bf2f(u16 h) {
  union { unsigned u; float f; } v; v.u = ((unsigned)h) << 16;
  return v.f;
}
__device__ __forceinline__ void gl2lds16(const void* g, void* l) {
  __builtin_amdgcn_global_load_lds(
      (__attribute__((address_space(1))) void*)(void*)g,
      (__attribute__((address_space(3))) void*)l, 16, 0, 0);
}

// ---------------------------------------------------------------------------
// Kernel 1: relu + channel-L2-norm scales + bf16 transpose to featT[b][p][ch].
// Stores in swizzled format: ch' = ch ^ (((p>>1)&3)<<3).
__global__ __launch_bounds__(256) void k_norm(const float* __restrict__ f1,
                                              const float* __restrict__ f2,
                                              u16* __restrict__ featT,
                                              float* __restrict__ s1,
                                              float* __restrict__ s2) {
  int bx = blockIdx.x;
  int b = bx >> 2;
  int p0 = (bx & 3) << 6;
  int t = threadIdx.x;
  int p = p0 + (t & 63);
  int cg = t >> 6;
  int sp3 = ((p >> 1) & 3) << 3;
  const float* F1 = f1 + ((size_t)b << 16);
  const float* F2 = f2 + ((size_t)b << 16);
  u16* FT = featT + (((size_t)(b << 8) + p) << 10);
  float ss1 = 0.f, ss2 = 0.f;
  for (int i = 0; i < 64; ++i) {
    int c = (cg << 6) + i;
    float v1 = F1[(c << 8) + p]; v1 = v1 > 0.f ? v1 : 0.f;
    float v2 = F2[(c << 8) + p]; v2 = v2 > 0.f ? v2 : 0.f;
    ss1 += v1 * v1; ss2 += v2 * v2;
    FT[c ^ sp3] = f2bf(v1);
    FT[512 + (c ^ sp3)] = f2bf(v2);
  }
  __shared__ float l1[256], l2[256];
  l1[t] = ss1; l2[t] = ss2;
  __syncthreads();
  if (t < 64) {
    float a = l1[t] + l1[t + 64] + l1[t + 128] + l1[t + 192];
    float c2 = l2[t] + l2[t + 64] + l2[t + 128] + l2[t + 192];
    int pp = (b << 8) + p0 + t;
    s1[pp] = 1.f / fmaxf(sqrtf(a), 1e-12f);
    s2[pp] = 1.f / fmaxf(sqrtf(c2), 1e-12f);
  }
}

// ---------------------------------------------------------------------------
// Kernel 2: weight repack fp32 [O][C][3][3] -> bf16 [tap][O][C], swizzled:
// c' = c ^ (((o>>1)&3)<<3).
__global__ __launch_bounds__(256) void k_wconv(const float* __restrict__ w,
                                               u16* __restrict__ wb, int O, int C) {
  int o = blockIdx.x;
  int t = threadIdx.x;
  int sp3 = ((o >> 1) & 3) << 3;
  const float* src = w + (size_t)o * C * 9;
  for (int c = t; c < C; c += 256) {
    const float* s = src + c * 9;
    float v[9];
#pragma unroll
    for (int i = 0; i < 9; ++i) v[i] = s[i];
#pragma unroll
    for (int tap = 0; tap < 9; ++tap)
      wb[(size_t)tap * O * C + (size_t)o * C + (c ^ sp3)] = f2bf(v[tap]);
  }
}

// ---------------------------------------------------------------------------
// Kernel 3: Gram GEMM G[p1][p2] = sum_c r1[p1][c]*r2[p2][c], scaled epilogue.
// (unchanged r4: 16x16x32 MFMA, monotonic staging, swizzled read chunk)
__global__ __launch_bounds__(256) void k_corr(u16* featT,
                                              const float* __restrict__ s1,
                                              const float* __restrict__ s2,
                                              float* __restrict__ out) {
  __shared__ alignas(16) u16 Alds[128 * 32];
  __shared__ alignas(16) u16 Blds[128 * 32];
  __shared__ float tb[4][16][66];
  int bx = blockIdx.x;
  int b = bx >> 2;
  int p1b = ((bx >> 1) & 1) << 7;
  int p2b = (bx & 1) << 7;
  int t = threadIdx.x, l = t & 63, w = t >> 6;
  int wm = w >> 1, wn = w & 1, lr = l & 15, lq = l >> 4;
  int srow = (w << 4) + (l >> 2);
  int sq = (l & 3) << 3;                       // monotonic source chunk
  int rsz = ((lq ^ ((lr >> 1) & 3)) << 3);     // swizzled read chunk
  const size_t bbase = (size_t)b << 18;

  f32x4 acc[4][4];
#pragma unroll
  for (int i = 0; i < 4; ++i)
#pragma unroll
    for (int j = 0; j < 4; ++j) acc[i][j] = (f32x4){0.f, 0.f, 0.f, 0.f};

#pragma unroll 1
  for (int kc = 0; kc < 8; ++kc) {
    int c0 = kc << 5;
    const u16* sA = featT + bbase + ((size_t)(p1b + srow) << 10) + (c0 + sq);
    gl2lds16(sA, Alds + ((w << 4) << 5));
    gl2lds16(sA + (64 << 10), Alds + ((64 + (w << 4)) << 5));
    const u16* sB = featT + bbase + ((size_t)(p2b + srow) << 10) + (512 + c0 + sq);
    gl2lds16(sB, Blds + ((w << 4) << 5));
    gl2lds16(sB + (64 << 10), Blds + ((64 + (w << 4)) << 5));
    __syncthreads();
    bf16x8 af[4], bfr[4];
#pragma unroll
    for (int mf = 0; mf < 4; ++mf)
      af[mf] = *(const bf16x8*)(Alds + (((wm << 6) + (mf << 4) + lr) << 5) + rsz);
#pragma unroll
    for (int nf = 0; nf < 4; ++nf)
      bfr[nf] = *(const bf16x8*)(Blds + (((wn << 6) + (nf << 4) + lr) << 5) + rsz);
#pragma unroll
    for (int mf = 0; mf < 4; ++mf)
#pragma unroll
      for (int nf = 0; nf < 4; ++nf)
        acc[mf][nf] = __builtin_amdgcn_mfma_f32_16x16x32_bf16(af[mf], bfr[nf], acc[mf][nf], 0, 0, 0);
    __syncthreads();
  }

  float sc2[4]; int p2g[4];
#pragma unroll
  for (int nf = 0; nf < 4; ++nf) {
    int p2 = p2b + (wn << 6) + (nf << 4) + lr;
    p2g[nf] = p2;
    sc2[nf] = s2[(b << 8) + p2];
  }
  float* corr1 = out + 512;
  float* corr2 = out + 512 + 16777216;
#pragma unroll
  for (int mf = 0; mf < 4; ++mf) {
    float gv[4][4];
#pragma unroll
    for (int r = 0; r < 4; ++r) {
      int p1 = p1b + (wm << 6) + (mf << 4) + (lq << 2) + r;
      float s1v = s1[(b << 8) + p1];
#pragma unroll
      for (int nf = 0; nf < 4; ++nf) gv[nf][r] = acc[mf][nf][r] * s1v * sc2[nf];
    }
#pragma unroll
    for (int r = 0; r < 4; ++r) {
      int p1 = p1b + (wm << 6) + (mf << 4) + (lq << 2) + r;
      int s1p3 = ((p1 >> 1) & 3) << 3;
#pragma unroll
      for (int nf = 0; nf < 4; ++nf) {
        corr2[((size_t)b << 16) + ((size_t)p1 << 8) + p2g[nf]] = gv[nf][r];
        featT[bbase + ((size_t)p1 << 10) + 256 + (p2g[nf] ^ s1p3)] = f2bf(gv[nf][r]);
      }
    }
#pragma unroll
    for (int r = 0; r < 4; ++r)
#pragma unroll
      for (int nf = 0; nf < 4; ++nf)
        tb[w][(lq << 2) + r][(nf << 4) + lr] = gv[nf][r];
#pragma unroll
    for (int j = 0; j < 16; ++j) {
      float v = tb[w][lr][(j << 2) + lq];
      int p2 = p2b + (wn << 6) + (j << 2) + lq;
      int s2p3 = ((p2 >> 1) & 3) << 3;
      int p1 = p1b + (wm << 6) + (mf << 4) + lr;
      corr1[((size_t)b << 16) + ((size_t)p2 << 8) + p1] = v;
      featT[bbase + ((size_t)p2 << 10) + 768 + (p1 ^ s2p3)] = f2bf(v);
    }
  }
}

// ---------------------------------------------------------------------------
// Kernel 4/5: implicit-GEMM 3x3 conv (r4 structure, W depth-3, setprio MFMA).
// Block = whole image M=256 x N=128 o, 512 threads = 8 waves (4M x 2N) 64x64.
// Step s=(kc,tap): issue W(s+3) -> Wlds[(kc+tap+3)&3]; tap0: stage X(kc+1);
// read frags from Wlds[(kc+tap)&3] + X kc-parity buffer; MFMA (setprio 1).
// Pre-barrier: vmcnt(4) taps 0-2, vmcnt(2) taps 3-8 (FIFO in header).
// Epilogue: per-wave LDS transpose -> merged uint4 stores in swizzled format.
template <int O, int OTB>
__global__ __launch_bounds__(512, 4) void k_conv(const u16* __restrict__ X,
                                                 const u16* __restrict__ Wb,
                                                 const float* __restrict__ bias,
                                                 u16* __restrict__ Out) {
  __shared__ alignas(16) u16 Xlds[2][260 * 32];  // rows 0..255 data, row 256 = zeros
  __shared__ alignas(16) u16 Wlds[4][128 * 32];
  int bx = blockIdx.x;
  int otile = bx & ((1 << OTB) - 1);   // low bits -> XCD affinity for the W slice
  int b = bx >> OTB;
  int t = threadIdx.x, l = t & 63, w = t >> 6;
  int wm = w & 3, wn = w >> 2;
  int lr = l & 15, lq = l >> 4;
  int o0 = otile << 7;
  int srl = l >> 2;
  int sq = (l & 3) << 3;               // monotonic source chunk
  const size_t xbase = (size_t)b << 18;

  const u16* wsrc = Wb + (((size_t)(o0 + (w << 4) + srl)) << 10) + sq;
  const u16* xsrc0 = X + xbase + (((size_t)((w << 4) + srl)) << 10) + sq;
  const u16* xsrc1 = xsrc0 + ((size_t)128 << 10);

  u16* wdst0 = &Wlds[0][(w << 4) << 5];
  u16* wdst1 = &Wlds[1][(w << 4) << 5];
  u16* wdst2 = &Wlds[2][(w << 4) << 5];
  u16* wdst3 = &Wlds[3][(w << 4) << 5];
  u16* xdA0 = &Xlds[0][(w << 4) << 5];
  u16* xdA1 = &Xlds[0][(128 + (w << 4)) << 5];
  u16* xdB0 = &Xlds[1][(w << 4) << 5];
  u16* xdB1 = &Xlds[1][(128 + (w << 4)) << 5];

  // W read: row = (wn<<6)+(nf<<4)+lr -> stored swizzle ((row>>1)&3) == ((lr>>1)&3).
  int rszw = ((lq ^ ((lr >> 1) & 3)) << 3);
  const u16* bwb0 = &Wlds[0][(((wn << 6) + lr) << 5) + rszw];
  const u16* bwb1 = &Wlds[1][(((wn << 6) + lr) << 5) + rszw];
  const u16* bwb2 = &Wlds[2][(((wn << 6) + lr) << 5) + rszw];
  const u16* bwb3 = &Wlds[3][(((wn << 6) + lr) << 5) + rszw];

  // X read swizzle variants indexed by dc (storage keyed on row = pixel).
  int pb[4];
#pragma unroll
  for (int mf = 0; mf < 4; ++mf)
    pb[mf] = (((wm << 6) + (mf << 4) + lr) << 5);
  int xsz[3];
#pragma unroll
  for (int d = 0; d < 3; ++d)
    xsz[d] = ((lq ^ (((lr + d - 1) >> 1) & 3)) << 3);
  const int zoff = (256 << 5) + (lq << 3);   // zero row: any chunk is zeros

  f32x4 acc[4][4];
#pragma unroll
  for (int i = 0; i < 4; ++i)
#pragma unroll
    for (int j = 0; j < 4; ++j) acc[i][j] = (f32x4){0.f, 0.f, 0.f, 0.f};

  if (t < 32) ((unsigned*)&Xlds[t >> 4][256 << 5])[t & 15] = 0u;

  // prologue: X(0) -> Xbuf0; W(step0..2) -> bufs 0,1,2.
  // Queue: X,X,W0,W1,W2 -> vmcnt(2) drains X+W0, leaves W1,W2 (invariant entry T0).
  gl2lds16(xsrc0, xdA0);
  gl2lds16(xsrc1, xdA1);
  gl2lds16(wsrc, wdst0);
  gl2lds16(wsrc + ((size_t)O << 10), wdst1);
  gl2lds16(wsrc + 2 * ((size_t)O << 10), wdst2);
  asm volatile("s_waitcnt vmcnt(2) lgkmcnt(0)" ::: "memory");
  __builtin_amdgcn_s_barrier();

  auto kcbody = [&](auto km4c, int kc) {
    constexpr int KM4 = decltype(km4c)::value;   // kc & 3
    const u16* xb = (KM4 & 1) ? &Xlds[1][0] : &Xlds[0][0];
#pragma unroll
    for (int tap = 0; tap < 9; ++tap) {
      __builtin_amdgcn_sched_barrier(0);
      // --- issue W(s+3) into buf (kc+tap+3)&3 (read for step s+3) ---
      {
        int ntap = (tap + 3 > 8) ? (tap - 6) : (tap + 3);
        int nkc = (tap >= 6) ? (kc + 1) : kc;   // kc=31 tail: in-ws garbage, dead
        constexpr int WB = (KM4 + 3) & 3;       // + tap handled below
        u16* wd = (((WB + tap) & 3) == 0) ? wdst0
                : ((((WB + tap) & 3) == 1) ? wdst1
                : ((((WB + tap) & 3) == 2) ? wdst2 : wdst3));
        gl2lds16(wsrc + (size_t)ntap * ((size_t)O << 10) + (nkc << 5), wd);
      }
      if (tap == 0) {  // stage X(kc+1) into other parity buffer
        if (KM4 & 1) { gl2lds16(xsrc0 + ((kc + 1) << 5), xdA0); gl2lds16(xsrc1 + ((kc + 1) << 5), xdA1); }
        else         { gl2lds16(xsrc0 + ((kc + 1) << 5), xdB0); gl2lds16(xsrc1 + ((kc + 1) << 5), xdB1); }
      }
      // --- fragment reads for this step from buf (kc+tap)&3 ---
      const u16* bwb = (((KM4 + tap) & 3) == 0) ? bwb0
                     : ((((KM4 + tap) & 3) == 1) ? bwb1
                     : ((((KM4 + tap) & 3) == 2) ? bwb2 : bwb3));
      bf16x8 bwf[4];
#pragma unroll
      for (int nf = 0; nf < 4; ++nf) bwf[nf] = *(const bf16x8*)(bwb + (nf << 9));
      const int dr = tap / 3 - 1, dc = tap % 3 - 1;
      const int dpo = (((dr << 4) + dc) << 5) + xsz[dc + 1];
      bf16x8 axf[4];
#pragma unroll
      for (int mf = 0; mf < 4; ++mf) {
        int rr = (wm << 2) + mf + dr;
        bool v = ((unsigned)rr < 16u) & ((unsigned)(lr + dc) < 16u);
        int off = v ? (pb[mf] + dpo) : zoff;
        axf[mf] = *(const bf16x8*)(xb + off);
      }
      // --- MFMA (boost wave priority through the matrix cluster) ---
      __builtin_amdgcn_s_setprio(1);
#pragma unroll
      for (int mf = 0; mf < 4; ++mf)
#pragma unroll
        for (int nf = 0; nf < 4; ++nf)
          acc[mf][nf] = __builtin_amdgcn_mfma_f32_16x16x32_bf16(axf[mf], bwf[nf], acc[mf][nf], 0, 0, 0);
      __builtin_amdgcn_s_setprio(0);
      // --- counted pre-barrier wait (FIFO in header) ---
      if (tap <= 2) asm volatile("s_waitcnt vmcnt(4)" ::: "memory");
      else          asm volatile("s_waitcnt vmcnt(2)" ::: "memory");
      __builtin_amdgcn_s_barrier();
    }
  };

#pragma unroll 1
  for (int kc4 = 0; kc4 < 8; ++kc4) {
    kcbody(IC<0>{}, 4 * kc4);
    kcbody(IC<1>{}, 4 * kc4 + 1);
    kcbody(IC<2>{}, 4 * kc4 + 2);
    kcbody(IC<3>{}, 4 * kc4 + 3);
  }

  // ---- epilogue: per-wave LDS transpose -> vectorized swizzled stores ----
  __syncthreads();   // drain outstanding prefetch; LDS reusable as scratch
  float bv[4];
#pragma unroll
  for (int nf = 0; nf < 4; ++nf) bv[nf] = bias[o0 + (wn << 6) + (nf << 4) + lr];
  u16* scr = ((u16*)Xlds) + w * 1152;   // per-wave 16 rows x 72 u16
  int rr2 = l >> 2;                     // 4 lanes per row
  int kq = l & 3;
#pragma unroll
  for (int mf = 0; mf < 4; ++mf) {
#pragma unroll
    for (int r = 0; r < 4; ++r) {
      int rr = (lq << 2) + r;
#pragma unroll
      for (int nf = 0; nf < 4; ++nf) {
        float vv = acc[mf][nf][r] + bv[nf];
        scr[rr * 72 + (nf << 4) + lr] = f2bf(vv > 0.f ? vv : 0.f);
      }
    }
    asm volatile("s_waitcnt lgkmcnt(0)" ::: "memory");
    __builtin_amdgcn_sched_barrier(0);
    int p = (wm << 6) + (mf << 4) + rr2;
    int sp = (p >> 1) & 3;
    size_t rbase = (size_t)((b << 8) + p) * O + (size_t)(o0 + (wn << 6));
#pragma unroll
    for (int j = 0; j < 2; ++j) {
      int k = (j << 2) | kq;             // stored chunk (monotone per group)
      int kl = (j << 2) | (kq ^ sp);     // logical chunk held at stored slot k
      uint4 v = *(const uint4*)(scr + rr2 * 72 + (kl << 3));
      *(uint4*)(Out + rbase + (k << 3)) = v;
    }
    asm volatile("s_waitcnt lgkmcnt(0)" ::: "memory");
    __builtin_amdgcn_sched_barrier(0);
  }
}

// ---------------------------------------------------------------------------
// Kernel 6: cls head. score[b][c] = mean_p relu(dot(out2T[b][p], Wc[c*256+p])),
// softmax over c. X2 rows swizzled: read stored chunks MONOTONICALLY (coalesced)
// and permute the WEIGHT chunk index instead (w reads are per-lane scattered
// rows anyway, so the permutation is free).
__global__ __launch_bounds__(256) void k_cls(const u16* __restrict__ X2,
                                             const float* __restrict__ Wc,
                                             float* __restrict__ out) {
  int b = blockIdx.x, p = threadIdx.x;
  int s = (p >> 1) & 3;
  const uint4* xv = (const uint4*)(X2 + (((size_t)(b << 8) + p) << 9));
  const float4* w0 = (const float4*)(Wc + ((size_t)p << 9));
  const float4* w1 = (const float4*)(Wc + ((size_t)(256 + p) << 9));
  float a0 = 0.f, a1 = 0.f;
#pragma unroll 4
  for (int i = 0; i < 64; ++i) {
    uint4 u = xv[i];                      // monotonic stored chunk
    int il = (i & ~3) | ((i & 3) ^ s);    // logical chunk held at stored slot i
    float x0 = bf2f((u16)(u.x & 0xffffu)), x1 = bf2f((u16)(u.x >> 16));
    float x2 = bf2f((u16)(u.y & 0xffffu)), x3 = bf2f((u16)(u.y >> 16));
    float x4 = bf2f((u16)(u.z & 0xffffu)), x5 = bf2f((u16)(u.z >> 16));
    float x6 = bf2f((u16)(u.w & 0xffffu)), x7 = bf2f((u16)(u.w >> 16));
    float4 wa = w0[il * 2], wb = w0[il * 2 + 1];
    a0 += x0 * wa.x + x1 * wa.y + x2 * wa.z + x3 * wa.w +
          x4 * wb.x + x5 * wb.y + x6 * wb.z + x7 * wb.w;
    float4 wc4 = w1[il * 2], wd = w1[il * 2 + 1];
    a1 += x0 * wc4.x + x1 * wc4.y + x2 * wc4.z + x3 * wc4.w +
          x4 * wd.x + x5 * wd.y + x6 * wd.z + x7 * wd.w;
  }
  a0 = fmaxf(a0, 0.f);
  a1 = fmaxf(a1, 0.f);
  __shared__ float r0[256], r1[256];
  r0[p] = a0; r1[p] = a1;
  for (int sdx = 128; sdx > 0; sdx >>= 1) {
    __syncthreads();
    if (p < sdx) { r0[p] += r0[p + sdx]; r1[p] += r1[p + sdx]; }
  }
  __syncthreads();
  if (p == 0) {
    float s0 = r0[0] * (1.f / 256.f), s1v = r1[0] * (1.f / 256.f);
    float m = fmaxf(s0, s1v);
    float e0 = expf(s0 - m), e1 = expf(s1v - m);
    float inv = 1.f / (e0 + e1);
    out[(b << 1) + 0] = e0 * inv;
    out[(b << 1) + 1] = e1 * inv;
  }
}

// ---------------------------------------------------------------------------
extern "C" void kernel_launch(void* const* d_in, const int* in_sizes, int n_in,
                              void* d_out, int out_size, void* d_ws, size_t ws_size,
                              hipStream_t stream) {
  const float* f1 = (const float*)d_in[0];
  const float* f2 = (const float*)d_in[1];
  const float* w1 = (const float*)d_in[2];
  const float* b1 = (const float*)d_in[3];
  const float* w2 = (const float*)d_in[4];
  const float* b2 = (const float*)d_in[5];
  const float* wc = (const float*)d_in[6];
  float* out = (float*)d_out;
  char* ws = (char*)d_ws;

  u16* featT = (u16*)(ws + 0);
  u16* out1T = (u16*)(ws + 134217728);
  u16* W1b   = (u16*)(ws + 268435456);
  u16* W2b   = (u16*)(ws + 287309824);
  float* s1  = (float*)(ws + 296747008);
  float* s2  = (float*)(ws + 297009152);
  u16* out2T = (u16*)(ws + 0);  // overlays featT (dead after conv1)

  k_norm<<<1024, 256, 0, stream>>>(f1, f2, featT, s1, s2);
  k_wconv<<<1024, 256, 0, stream>>>(w1, W1b, 1024, 1024);
  k_wconv<<<512, 256, 0, stream>>>(w2, W2b, 512, 1024);
  k_corr<<<1024, 256, 0, stream>>>(featT, s1, s2, out);
  k_conv<1024, 3><<<2048, 512, 0, stream>>>(featT, W1b, b1, out1T);
  k_conv<512, 2><<<1024, 512, 0, stream>>>(out1T, W2b, b2, out2T);
  k_cls<<<256, 256, 0, stream>>>(out2T, wc, out);
}